// Round 1
// baseline (121.741 us; speedup 1.0000x reference)
//
#include <hip/hip_runtime.h>

// StericClashConstraint: N=16384 points [N,3] fp32.
// out[0..3N-1] = pos (passthrough); out[3N] = mean(max(1-dist,0) over NxN, diag masked) * 0.02
//
// Strategy: compute-bound pairwise loop. Direct diff (not gram trick) in fp32.
// Diagonal contributes exactly 1.0 per point (d2==0) -> subtract N at the end.
// Rare-path sqrt guarded by wave vote (__any) — ~95% of wave-iters skip it.

constexpr int TI = 256;        // i's per block (one per thread)
constexpr int TJ = 256;        // j-tile staged in LDS
constexpr int NJ_CHUNKS = 16;  // j-range split for occupancy: 64 x 16 = 1024 blocks

__global__ void prep_kernel(const float* __restrict__ pos, float* __restrict__ out,
                            float* __restrict__ acc, int n_float4) {
    int t = blockIdx.x * blockDim.x + threadIdx.x;
    if (t < n_float4) {
        reinterpret_cast<float4*>(out)[t] = reinterpret_cast<const float4*>(pos)[t];
    }
    if (t == 0) *acc = 0.0f;
}

__global__ void __launch_bounds__(256) pair_kernel(const float* __restrict__ pos,
                                                   float* __restrict__ acc, int n) {
    __shared__ float4 sx4[TJ / 4];
    __shared__ float4 sy4[TJ / 4];
    __shared__ float4 sz4[TJ / 4];

    const int t = threadIdx.x;
    const int i = blockIdx.x * TI + t;

    const float xi = pos[i * 3 + 0];
    const float yi = pos[i * 3 + 1];
    const float zi = pos[i * 3 + 2];

    float s = 0.0f;

    const int jchunk = n / NJ_CHUNKS;           // 1024
    const int j0 = blockIdx.y * jchunk;

    for (int jb = j0; jb < j0 + jchunk; jb += TJ) {
        __syncthreads();
        // stage TJ j-points into LDS (SoA so inner loop reads float4 quads)
        const float* p = pos + (size_t)(jb + t) * 3;
        reinterpret_cast<float*>(sx4)[t] = p[0];
        reinterpret_cast<float*>(sy4)[t] = p[1];
        reinterpret_cast<float*>(sz4)[t] = p[2];
        __syncthreads();

        #pragma unroll 4
        for (int q = 0; q < TJ / 4; ++q) {
            const float4 x4 = sx4[q];   // broadcast reads: all lanes same addr, no conflicts
            const float4 y4 = sy4[q];
            const float4 z4 = sz4[q];

            float dx, dy, dz;
            dx = xi - x4.x; dy = yi - y4.x; dz = zi - z4.x;
            const float da = fmaf(dx, dx, fmaf(dy, dy, dz * dz));
            dx = xi - x4.y; dy = yi - y4.y; dz = zi - z4.y;
            const float db = fmaf(dx, dx, fmaf(dy, dy, dz * dz));
            dx = xi - x4.z; dy = yi - y4.z; dz = zi - z4.z;
            const float dc = fmaf(dx, dx, fmaf(dy, dy, dz * dz));
            dx = xi - x4.w; dy = yi - y4.w; dz = zi - z4.w;
            const float dd = fmaf(dx, dx, fmaf(dy, dy, dz * dz));

            const float m = fminf(fminf(da, db), fminf(dc, dd));
            if (__any(m < 1.0f)) {              // rare path: ~5% of wave-iterations
                if (da < 1.0f) s += 1.0f - sqrtf(da);
                if (db < 1.0f) s += 1.0f - sqrtf(db);
                if (dc < 1.0f) s += 1.0f - sqrtf(dc);
                if (dd < 1.0f) s += 1.0f - sqrtf(dd);
            }
        }
    }

    // wave reduce (64 lanes), then cross-wave via LDS, one atomic per block
    for (int off = 32; off > 0; off >>= 1) s += __shfl_down(s, off);
    __shared__ float wsum[TI / 64];
    __syncthreads();
    if ((t & 63) == 0) wsum[t >> 6] = s;
    __syncthreads();
    if (t == 0) {
        float bs = 0.0f;
        #pragma unroll
        for (int w = 0; w < TI / 64; ++w) bs += wsum[w];
        atomicAdd(acc, bs);
    }
}

__global__ void finalize_kernel(const float* __restrict__ acc, float* __restrict__ out, int n) {
    // remove diagonal (each i==j contributed exactly 1.0), then mean * weight
    const double sum = (double)(*acc) - (double)n;
    const double nn = (double)n * (double)n;
    out[(size_t)n * 3] = (float)(sum / nn * 0.02);
}

extern "C" void kernel_launch(void* const* d_in, const int* in_sizes, int n_in,
                              void* d_out, int out_size, void* d_ws, size_t ws_size,
                              hipStream_t stream) {
    const float* pos = (const float*)d_in[0];
    float* out = (float*)d_out;
    float* acc = (float*)d_ws;

    const int n = in_sizes[0] / 3;          // 16384
    const int n_float4 = (n * 3) / 4;       // 12288

    dim3 gridA((n_float4 + 255) / 256);
    prep_kernel<<<gridA, 256, 0, stream>>>(pos, out, acc, n_float4);

    dim3 gridB(n / TI, NJ_CHUNKS);
    pair_kernel<<<gridB, 256, 0, stream>>>(pos, acc, n);

    finalize_kernel<<<1, 1, 0, stream>>>(acc, out, n);
}

// Round 2
// 119.827 us; speedup vs baseline: 1.0160x; 1.0160x over previous
//
#include <hip/hip_runtime.h>

// StericClashConstraint: N=16384 pts [N,3] fp32.
// out[0..3N-1] = pos passthrough; out[3N] = mean(max(1-dist,0), diag=0) * 0.02
//
// Round 2: gram trick (4 VALU/pair common path), IPT=8 register tile with
// packed float4{x,y,z,|p|^2} LDS j-tile (2 B LDS/pair vs 12 in R1 — R1 was
// LDS-return-bandwidth bound), single kernel with last-block-done epilogue.
// Diagonal excluded exactly via j!=i test in the rare (voted) path.

constexpr int BLOCK = 256;
constexpr int IPT   = 8;    // i's per thread
constexpr int TJ    = 64;   // j's per block (one LDS tile, staged once)

__global__ void __launch_bounds__(BLOCK, 6)
pair_kernel(const float* __restrict__ pos, float* __restrict__ out,
            float* __restrict__ acc, unsigned int* __restrict__ cnt, int n) {
    __shared__ float4 tile[TJ];
    __shared__ float  wsum[BLOCK / 64];

    const int t   = threadIdx.x;
    const int ibx = blockIdx.x;
    const int jby = blockIdx.y;

    // pos -> out passthrough, folded into the y==0 block column
    if (jby == 0) {
        const float4* p4 = reinterpret_cast<const float4*>(pos);
        float4*       o4 = reinterpret_cast<float4*>(out);
        const int total4 = (n * 3) / 4;
        const int stride = gridDim.x * BLOCK;
        for (int idx = ibx * BLOCK + t; idx < total4; idx += stride)
            o4[idx] = p4[idx];
    }

    // stage j-tile: {x, y, z, |p|^2} per point
    const int j0 = jby * TJ;
    if (t < TJ) {
        const float* p = pos + (size_t)(j0 + t) * 3;
        const float x = p[0], y = p[1], z = p[2];
        tile[t] = make_float4(x, y, z, fmaf(x, x, fmaf(y, y, z * z)));
    }

    // per-thread i fragments (gram form): d2 = (sqj - 2*dot) + sqi
    // common-path test: (sqj - 2*dot) < 1 - sqi  == thr
    const int iBase = ibx * (BLOCK * IPT);
    const int ibt   = iBase + t;
    float xi2[IPT], yi2[IPT], zi2[IPT], thr[IPT];
    #pragma unroll
    for (int k = 0; k < IPT; ++k) {
        const float* p = pos + (size_t)(ibt + k * BLOCK) * 3;
        const float x = p[0], y = p[1], z = p[2];
        xi2[k] = -2.0f * x;
        yi2[k] = -2.0f * y;
        zi2[k] = -2.0f * z;
        thr[k] = 1.0f - fmaf(x, x, fmaf(y, y, z * z));
    }

    __syncthreads();

    float s = 0.0f;
    float4 pj = tile[0];
    for (int q = 0; q < TJ; ++q) {
        const float4 pjn = tile[(q + 1) & (TJ - 1)];  // prefetch next (wraps harmlessly)
        float tt[IPT];
        bool  v = false;
        #pragma unroll
        for (int k = 0; k < IPT; ++k) {
            float d = fmaf(xi2[k], pj.x, pj.w);
            d = fmaf(yi2[k], pj.y, d);
            d = fmaf(zi2[k], pj.z, d);
            tt[k] = d;
            v |= (d < thr[k]);
        }
        if (__any(v)) {                    // ~32% of wave-iterations
            const int jj = j0 + q;
            #pragma unroll
            for (int k = 0; k < IPT; ++k) {
                if (tt[k] < thr[k] && jj != ibt + k * BLOCK) {
                    const float d2 = fmaxf(tt[k] + (1.0f - thr[k]), 0.0f);
                    s += 1.0f - sqrtf(d2);
                }
            }
        }
        pj = pjn;
    }

    // wave reduce -> cross-wave LDS -> one atomic per block
    for (int off = 32; off > 0; off >>= 1) s += __shfl_down(s, off);
    if ((t & 63) == 0) wsum[t >> 6] = s;
    __syncthreads();
    if (t == 0) {
        float bs = 0.0f;
        #pragma unroll
        for (int w = 0; w < BLOCK / 64; ++w) bs += wsum[w];
        atomicAdd(acc, bs);
        __threadfence();
        const unsigned int nblocks = gridDim.x * gridDim.y;
        const unsigned int done = atomicAdd(cnt, 1u);
        if (done == nblocks - 1u) {        // last block finalizes
            __threadfence();
            const float total = atomicAdd(acc, 0.0f);  // device-coherent read
            const double mean = (double)total / ((double)n * (double)n);
            out[(size_t)n * 3] = (float)(mean * 0.02);
        }
    }
}

extern "C" void kernel_launch(void* const* d_in, const int* in_sizes, int n_in,
                              void* d_out, int out_size, void* d_ws, size_t ws_size,
                              hipStream_t stream) {
    const float* pos = (const float*)d_in[0];
    float* out = (float*)d_out;
    float* acc = (float*)d_ws;
    unsigned int* cnt = (unsigned int*)d_ws + 1;

    const int n = in_sizes[0] / 3;          // 16384

    hipMemsetAsync(d_ws, 0, 8, stream);     // acc = 0.f, cnt = 0

    dim3 grid(n / (BLOCK * IPT), n / TJ);   // (8, 256) = 2048 blocks
    pair_kernel<<<grid, BLOCK, 0, stream>>>(pos, out, acc, cnt, n);
}